// Round 1
// baseline (694.289 us; speedup 1.0000x reference)
//
#include <hip/hip_runtime.h>
#include <math.h>

// Problem constants (P, C, NX, NY, NT) = (2, 1, 128, 128, 8), T = 128
#define NTOT (2 * 128 * 128 * 8)   // 262144 sites
#define TSTEPS 128

// Layout: idx = pp*(128*128*8) + ix*(128*8) + iy*8 + it
//   it stride = 1, iy stride = 8 (1<<3), ix stride = 1024 (1<<10), pp stride = 1<<17

template <bool FIRST, bool LAST>
__global__ __launch_bounds__(256) void pdhg_step(
    const float* __restrict__ x,        // xnoisy (pristine input, also the t=0 state)
    const float* __restrict__ lam,
    const float* __restrict__ tau_p,
    const float* __restrict__ sigma_p,
    const float* __restrict__ theta_p,
    const float* __restrict__ xbar_in,
    const float* __restrict__ q0_in,
    const float* __restrict__ q1_in,
    const float* __restrict__ q2_in,
    float* __restrict__ x0,             // in/out: read x0_old, write x1
    float* __restrict__ p,              // in/out (self-site only)
    float* __restrict__ xbar_out,
    float* __restrict__ q0_out,
    float* __restrict__ q1_out,
    float* __restrict__ q2_out,
    float* __restrict__ out_final)
{
    const int idx = blockIdx.x * 256 + threadIdx.x;

    const int it = idx & 7;
    const int iy = (idx >> 3) & 127;
    const int ix = (idx >> 10) & 127;

    // periodic neighbor flat indices
    const int i_xp = idx + ((ix == 127) ? -(127 << 10) : (1 << 10));
    const int i_xm = idx + ((ix == 0)   ?  (127 << 10) : -(1 << 10));
    const int i_yp = idx + ((iy == 127) ? -(127 << 3)  : (1 << 3));
    const int i_ym = idx + ((iy == 0)   ?  (127 << 3)  : -(1 << 3));
    const int i_tp = idx + ((it == 7)   ? -7 : 1);
    const int i_tm = idx + ((it == 0)   ?  7 : -1);

    // uniform scalars (broadcast loads)
    const float L = 3.605551275463989f;  // sqrt(13)
    const float s_sig = (1.f / (1.f + __expf(-sigma_p[0]))) / L;
    const float s_tau = (1.f / (1.f + __expf(-tau_p[0]))) / L;
    const float s_th  =  1.f / (1.f + __expf(-theta_p[0]));
    const float inv1s = 1.f / (1.f + s_sig);

    const float xn_c = x[idx];

    float xb_c, xb_xp, xb_xm, xb_yp, xb_ym, xb_tp, xb_tm;
    float p_old, x0_old, q0c, q1c, q2c, q0xm, q1ym, q2tm;

    if (FIRST) {
        // initial state: xbar = p = x0 = x, q = 0
        xb_c  = xn_c;
        xb_xp = x[i_xp]; xb_xm = x[i_xm];
        xb_yp = x[i_yp]; xb_ym = x[i_ym];
        xb_tp = x[i_tp]; xb_tm = x[i_tm];
        p_old = xn_c; x0_old = xn_c;
        q0c = q1c = q2c = q0xm = q1ym = q2tm = 0.f;
    } else {
        xb_c  = xbar_in[idx];
        xb_xp = xbar_in[i_xp]; xb_xm = xbar_in[i_xm];
        xb_yp = xbar_in[i_yp]; xb_ym = xbar_in[i_ym];
        xb_tp = xbar_in[i_tp]; xb_tm = xbar_in[i_tm];
        p_old = p[idx]; x0_old = x0[idx];
        q0c  = q0_in[idx];  q1c  = q1_in[idx];  q2c  = q2_in[idx];
        q0xm = q0_in[i_xm]; q1ym = q1_in[i_ym]; q2tm = q2_in[i_tm];
    }

    const float lam_c  = lam[idx];
    const float lam_xm = lam[i_xm];
    const float lam_ym = lam[i_ym];
    const float lam_tm = lam[i_tm];

    // p update (local)
    const float p_new = (p_old + s_sig * (xb_c - xn_c)) * inv1s;

    // q update at this site (forward differences of xbar), clip to [-lam, lam]
    const float q0n = fmaxf(-lam_c, fminf(lam_c, q0c + s_sig * (xb_xp - xb_c)));
    const float q1n = fmaxf(-lam_c, fminf(lam_c, q1c + s_sig * (xb_yp - xb_c)));
    const float q2n = fmaxf(-lam_c, fminf(lam_c, q2c + s_sig * (xb_tp - xb_c)));

    // redundantly compute the backward neighbors' new q components (for divergence)
    const float q0nm = fmaxf(-lam_xm, fminf(lam_xm, q0xm + s_sig * (xb_c - xb_xm)));
    const float q1nm = fmaxf(-lam_ym, fminf(lam_ym, q1ym + s_sig * (xb_c - xb_ym)));
    const float q2nm = fmaxf(-lam_tm, fminf(lam_tm, q2tm + s_sig * (xb_c - xb_tm)));

    // grad_GH(q_new) at this site
    const float div = (q0nm - q0n) + (q1nm - q1n) + (q2nm - q2n);

    const float x1 = x0_old - s_tau * (p_new + div);

    if (!LAST) {
        p[idx] = p_new;
        q0_out[idx] = q0n; q1_out[idx] = q1n; q2_out[idx] = q2n;
        x0[idx] = x1;
        xbar_out[idx] = x1 + s_th * (x1 - x0_old);
    } else {
        out_final[idx] = x1;
    }
}

extern "C" void kernel_launch(void* const* d_in, const int* in_sizes, int n_in,
                              void* d_out, int out_size, void* d_ws, size_t ws_size,
                              hipStream_t stream) {
    const float* x   = (const float*)d_in[0];
    const float* lam = (const float*)d_in[1];
    const float* tau = (const float*)d_in[2];
    const float* sig = (const float*)d_in[3];
    const float* th  = (const float*)d_in[4];
    float* out = (float*)d_out;

    float* ws = (float*)d_ws;
    const int N = NTOT;
    // workspace layout: 10*N floats = 10 MB
    float* x0    = ws;
    float* p     = ws + (size_t)N;
    float* xb[2] = { ws + 2 * (size_t)N, ws + 3 * (size_t)N };
    float* q0[2] = { ws + 4 * (size_t)N, ws + 5 * (size_t)N };
    float* q1[2] = { ws + 6 * (size_t)N, ws + 7 * (size_t)N };
    float* q2[2] = { ws + 8 * (size_t)N, ws + 9 * (size_t)N };

    dim3 grid(N / 256), block(256);

    for (int i = 0; i < TSTEPS; ++i) {
        const int w = i & 1;
        const int r = w ^ 1;
        if (i == 0) {
            pdhg_step<true, false><<<grid, block, 0, stream>>>(
                x, lam, tau, sig, th,
                xb[r], q0[r], q1[r], q2[r],
                x0, p, xb[w], q0[w], q1[w], q2[w], out);
        } else if (i == TSTEPS - 1) {
            pdhg_step<false, true><<<grid, block, 0, stream>>>(
                x, lam, tau, sig, th,
                xb[r], q0[r], q1[r], q2[r],
                x0, p, xb[w], q0[w], q1[w], q2[w], out);
        } else {
            pdhg_step<false, false><<<grid, block, 0, stream>>>(
                x, lam, tau, sig, th,
                xb[r], q0[r], q1[r], q2[r],
                x0, p, xb[w], q0[w], q1[w], q2[w], out);
        }
    }
}